// Round 7
// baseline (625.311 us; speedup 1.0000x reference)
//
#include <hip/hip_runtime.h>
#include <math.h>

typedef unsigned int uint;
typedef unsigned short ushort;
typedef short s16x8 __attribute__((ext_vector_type(8)));
typedef float f32x4 __attribute__((ext_vector_type(4)));
typedef uint u32x4 __attribute__((ext_vector_type(4)));

#define L     880
#define LP    896
#define NC    64
#define WSZ   (NC * LP)
#define DS    48
#define OUTD  96
#define KCV   3072
#define NZ    3
#define NBLK  512

// ws layout (float offsets); 11 bf16 E planes then WF/WB/KDT/U/part/barrier
#define OFF_E    0
#define OFF_WF   4415488                    // 64 slabs f32
#define OFF_WB   (OFF_WF + 64 * WSZ)        // 64 slabs bf16
#define OFF_KDT  (OFF_WB + 64 * WSZ / 2)    // 896x3072 bf16
#define OFF_U    (OFF_KDT + LP * KCV / 2)   // 256x3072 bf16
#define OFF_PART (OFF_U + 256 * KCV / 2)    // NZ x 256 x 896 f32
#define OFF_BAR  (OFF_PART + NZ * 256 * LP) // 2 ints (cnt, gen)
// total ~49.5 MiB

__device__ inline ushort f2b(float f) {
  uint u = __builtin_bit_cast(uint, f);
  u += 0x7fffu + ((u >> 16) & 1u);
  return (ushort)(u >> 16);
}
__device__ inline float b2f(ushort b) {
  uint u = ((uint)b) << 16;
  return __builtin_bit_cast(float, u);
}

// ---- software grid barrier (all NBLK blocks co-resident by capacity) ----
__device__ __forceinline__ void gbar(int* cnt, int* gen, int target) {
  __syncthreads();
  if (threadIdx.x == 0) {
    __threadfence();                                   // release prior writes
    int prev = atomicAdd(cnt, 1);
    if (prev == NBLK - 1) {
      *cnt = 0;
      __threadfence();
      atomicAdd(gen, 1);
    } else {
      while (atomicAdd(gen, 0) < target) __builtin_amdgcn_s_sleep(2);
    }
    __threadfence();                                   // acquire
  }
  __syncthreads();
}

__global__ void k_init(int* bar) {
  if (threadIdx.x < 2) bar[threadIdx.x] = 0;
}

// ---- 64x64xK GEMM core (round-4 geometry): C[m][n] = sum_k Ag[m][k]*Bg[n][k] ----
__device__ __forceinline__ void gemm64(const ushort* __restrict__ Ag,
                                       const ushort* __restrict__ Bg,
                                       int Kdim, int kIters, int kOff, int m0, int n0,
                                       int tid, ushort (*As)[72], ushort (*Bs)[72],
                                       f32x4 acc[2][2]) {
  const int r = tid >> 2, kq = (tid & 3) * 16;
  const ushort* aptr = Ag + (size_t)(m0 + r) * Kdim + kOff + kq;
  const ushort* bptr = Bg + (size_t)(n0 + r) * Kdim + kOff + kq;
  const int wv = tid >> 6, lane = tid & 63;
  const int wm = (wv >> 1) * 32, wn = (wv & 1) * 32;
  const int lr = lane & 15, lg = lane >> 4;
  acc[0][0] = f32x4{0.f, 0.f, 0.f, 0.f};
  acc[0][1] = f32x4{0.f, 0.f, 0.f, 0.f};
  acc[1][0] = f32x4{0.f, 0.f, 0.f, 0.f};
  acc[1][1] = f32x4{0.f, 0.f, 0.f, 0.f};
  u32x4 ra0 = *(const u32x4*)aptr;
  u32x4 ra1 = *(const u32x4*)(aptr + 8);
  u32x4 rb0 = *(const u32x4*)bptr;
  u32x4 rb1 = *(const u32x4*)(bptr + 8);
  __syncthreads();                       // protect LDS vs previous task's readers
  for (int it = 0; it < kIters; ++it) {
    const int cur = (it & 1) * 64;
    *(u32x4*)&As[cur + r][kq]     = ra0;
    *(u32x4*)&As[cur + r][kq + 8] = ra1;
    *(u32x4*)&Bs[cur + r][kq]     = rb0;
    *(u32x4*)&Bs[cur + r][kq + 8] = rb1;
    __syncthreads();
    if (it + 1 < kIters) {
      ra0 = *(const u32x4*)(aptr + (it + 1) * 64);
      ra1 = *(const u32x4*)(aptr + (it + 1) * 64 + 8);
      rb0 = *(const u32x4*)(bptr + (it + 1) * 64);
      rb1 = *(const u32x4*)(bptr + (it + 1) * 64 + 8);
    }
#pragma unroll
    for (int k2 = 0; k2 < 2; ++k2) {
      s16x8 a0 = *(const s16x8*)&As[cur + wm + lr][k2 * 32 + lg * 8];
      s16x8 a1 = *(const s16x8*)&As[cur + wm + 16 + lr][k2 * 32 + lg * 8];
      s16x8 b0 = *(const s16x8*)&Bs[cur + wn + lr][k2 * 32 + lg * 8];
      s16x8 b1 = *(const s16x8*)&Bs[cur + wn + 16 + lr][k2 * 32 + lg * 8];
      acc[0][0] = __builtin_amdgcn_mfma_f32_16x16x32_bf16(a0, b0, acc[0][0], 0, 0, 0);
      acc[0][1] = __builtin_amdgcn_mfma_f32_16x16x32_bf16(a0, b1, acc[0][1], 0, 0, 0);
      acc[1][0] = __builtin_amdgcn_mfma_f32_16x16x32_bf16(a1, b0, acc[1][0], 0, 0, 0);
      acc[1][1] = __builtin_amdgcn_mfma_f32_16x16x32_bf16(a1, b1, acc[1][1], 0, 0, 0);
    }
  }
}

// ---- kd task: KDT[l0..+63][j*48+d] = W_j[d][l] - W_{j-1}[d][l] (j=63 -> zero pad) ----
__device__ __forceinline__ void kd_body(const float* __restrict__ WF, ushort* __restrict__ KDT,
                                        int j, int l0, int tid, float (*D)[65]) {
  __syncthreads();
  if (j < 63) {
    const float* Wj = WF + (size_t)j * WSZ;
    for (int e = tid; e < 48 * 64; e += 256) {
      int d = e >> 6, ll = e & 63;
      float v = Wj[d * LP + l0 + ll];
      if (j > 0) v -= Wj[-(int)WSZ + d * LP + l0 + ll];
      D[d][ll] = v;
    }
  } else {
    for (int e = tid; e < 48 * 64; e += 256) { int d = e >> 6, ll = e & 63; D[d][ll] = 0.f; }
  }
  __syncthreads();
  for (int e = tid; e < 48 * 64; e += 256) {
    int ll = e / 48, d = e - ll * 48;
    KDT[(size_t)(l0 + ll) * KCV + j * 48 + d] = f2b(D[d][ll]);
  }
  __syncthreads();
}

__global__ __launch_bounds__(256, 2) void mega(const float* __restrict__ xs,
                                               const float* __restrict__ ts,
                                               const float* __restrict__ th0,
                                               const float* __restrict__ A,
                                               const float* __restrict__ B,
                                               float* __restrict__ ws,
                                               float* __restrict__ out) {
  __shared__ __align__(16) unsigned char smemRaw[36864];
  ushort (*As)[72] = (ushort(*)[72])smemRaw;             // 128 rows (2 bufs x 64)
  ushort (*Bs)[72] = (ushort(*)[72])(smemRaw + 18432);
  const int tid = threadIdx.x;
  const int bid = blockIdx.x;
  const int nb  = gridDim.x;

  ushort* EP = (ushort*)(ws + OFF_E);
  const size_t PL = (size_t)LP * LP;
  ushort* EN[6]; ushort* ET[5];
#pragma unroll
  for (int i = 0; i < 5; ++i) { EN[i] = EP + (size_t)(2 * i) * PL; ET[i] = EP + (size_t)(2 * i + 1) * PL; }
  EN[5] = EP + 10 * PL;
  float*  WF   = ws + OFF_WF;
  ushort* WB   = (ushort*)(ws + OFF_WB);
  ushort* KDT  = (ushort*)(ws + OFF_KDT);
  ushort* U    = (ushort*)(ws + OFF_U);
  float*  part = ws + OFF_PART;
  int*    bar  = (int*)(ws + OFF_BAR);
  int*    cnt  = bar;
  int*    gen  = bar + 1;
  int     barid = 0;
  float cp[6];
  cp[0] = 0.99f;
#pragma unroll
  for (int i = 1; i < 6; ++i) cp[i] = cp[i - 1] * cp[i - 1];

  // ================= P0: prep (E1: 196 | W0: 14 | U: 192) =================
  for (int task = bid; task < 402; task += nb) {
    if (task < 196) {
      float (*T)[65] = (float(*)[65])smemRaw;
      const int bi = (task / 14) * 64, bj = (task % 14) * 64;
      const int r = tid >> 2, c0 = (tid & 3) * 16;
      const int gi = bi + r;
      __syncthreads();
#pragma unroll
      for (int q = 0; q < 4; ++q) {
        int c = c0 + q * 4, gj = bj + c;
        float4 v = {0.f, 0.f, 0.f, 0.f};
        if (gi < L && gj + 3 < L) {
          v = *(const float4*)(A + (size_t)gi * L + gj);
        } else if (gi < L) {
          if (gj + 0 < L) v.x = A[(size_t)gi * L + gj];
          if (gj + 1 < L) v.y = A[(size_t)gi * L + gj + 1];
          if (gj + 2 < L) v.z = A[(size_t)gi * L + gj + 2];
          if (gj + 3 < L) v.w = A[(size_t)gi * L + gj + 3];
        }
        if (gi == gj)     v.x -= 0.99f;
        if (gi == gj + 1) v.y -= 0.99f;
        if (gi == gj + 2) v.z -= 0.99f;
        if (gi == gj + 3) v.w -= 0.99f;
        T[r][c] = v.x; T[r][c + 1] = v.y; T[r][c + 2] = v.z; T[r][c + 3] = v.w;
      }
      __syncthreads();
      {
        union { ushort s[16]; u32x4 v[2]; } pk;
#pragma unroll
        for (int i = 0; i < 16; ++i) pk.s[i] = f2b(T[r][c0 + i]);
        *(u32x4*)(EN[0] + (size_t)(bi + r) * LP + bj + c0)     = pk.v[0];
        *(u32x4*)(EN[0] + (size_t)(bi + r) * LP + bj + c0 + 8) = pk.v[1];
      }
      {
        union { ushort s[16]; u32x4 v[2]; } pk;
#pragma unroll
        for (int i = 0; i < 16; ++i) pk.s[i] = f2b(T[c0 + i][r]);
        *(u32x4*)(ET[0] + (size_t)(bj + r) * LP + bi + c0)     = pk.v[0];
        *(u32x4*)(ET[0] + (size_t)(bj + r) * LP + bi + c0 + 8) = pk.v[1];
      }
      __syncthreads();
    } else if (task < 210) {
      int base = (task - 196) * 4096;
      for (int e = tid; e < 4096; e += 256) {
        int idx = base + e;
        int c = idx / LP, l = idx % LP;
        float v = 0.f;
        if (l < L) {
          if (c < DS) v = B[l * DS + c];
          else if (c == DS) v = th0[l];
          else if (c < 53) {
            int b = c - 49;
            float s = 0.f;
            for (int d = 0; d < DS; ++d) s += B[l * DS + d] * xs[(b * 64) * DS + d];
            v = -s;
          }
        }
        WF[idx] = v;
        WB[idx] = f2b(v);
      }
    } else {
      int idx0 = ((task - 210) * 256 + tid) * 16;   // 192 tasks cover 256*KCV
      int rr = idx0 / KCV, k = idx0 % KCV;
      u32x4 o0 = {}, o1 = {};
      if (rr < 252 && k < 3024) {
        int b = rr / 63, tau = rr - b * 63;
        int j = k / DS, d0 = k - j * DS;            // d0 in {0,16,32}
        int s = tau - j; if (s < 0) s += 63;
        const float* xp = xs + (size_t)(b * 64 + s + 1) * DS + d0;
        union { ushort u[16]; u32x4 v[2]; } pk;
#pragma unroll
        for (int q = 0; q < 16; ++q) pk.u[q] = f2b(xp[q]);
        o0 = pk.v[0]; o1 = pk.v[1];
      }
      *(u32x4*)(U + idx0)     = o0;
      *(u32x4*)(U + idx0 + 8) = o1;
    }
  }
  gbar(cnt, gen, ++barid);

  // ====== P1..P5: [sq E_S -> E_2S] || [chain W_{t+S} = c_S W_t + W_t E_S] ======
  for (int lev = 0; lev < 5; ++lev) {
    const int S = 1 << lev;
    const int ntask = 196 + S * 14;
    const float csq = 2.f * cp[lev];
    const float cch = cp[lev];
    for (int task = bid; task < ntask; task += nb) {
      f32x4 acc[2][2];
      const int wv = tid >> 6, lane = tid & 63;
      const int wm = (wv >> 1) * 32, wn = (wv & 1) * 32;
      const int lr = lane & 15, lg = lane >> 4;
      if (task < 196) {
        const int m0 = (task / 14) * 64, n0 = (task % 14) * 64;
        gemm64(EN[lev], ET[lev], LP, 14, 0, m0, n0, tid, As, Bs, acc);
        ushort (*T)[72] = As;
        __syncthreads();
#pragma unroll
        for (int fm = 0; fm < 2; ++fm)
#pragma unroll
          for (int fn = 0; fn < 2; ++fn)
#pragma unroll
            for (int rr = 0; rr < 4; ++rr) {
              int mi = wm + fm * 16 + lg * 4 + rr;
              int ni = wn + fn * 16 + lr;
              float v = acc[fm][fn][rr] + csq * b2f(EN[lev][(size_t)(m0 + mi) * LP + n0 + ni]);
              ushort bv = f2b(v);
              EN[lev + 1][(size_t)(m0 + mi) * LP + n0 + ni] = bv;
              T[ni][mi] = bv;
            }
        if (lev < 4) {
          __syncthreads();
          const int nr = tid >> 2, ct0 = (tid & 3) * 16;
          u32x4 o0 = *(const u32x4*)&T[nr][ct0];
          u32x4 o1 = *(const u32x4*)&T[nr][ct0 + 8];
          *(u32x4*)(ET[lev + 1] + (size_t)(n0 + nr) * LP + m0 + ct0)     = o0;
          *(u32x4*)(ET[lev + 1] + (size_t)(n0 + nr) * LP + m0 + ct0 + 8) = o1;
        }
        __syncthreads();
      } else {
        const int ct = task - 196;
        const int t = ct / 14, n0 = (ct % 14) * 64;
        gemm64(WB + (size_t)t * WSZ, EN[lev], LP, 14, 0, 0, n0, tid, As, Bs, acc);
        const size_t srcO = (size_t)t * WSZ, dstO = (size_t)(t + S) * WSZ;
#pragma unroll
        for (int fm = 0; fm < 2; ++fm)
#pragma unroll
          for (int fn = 0; fn < 2; ++fn)
#pragma unroll
            for (int rr = 0; rr < 4; ++rr) {
              int mi = wm + fm * 16 + lg * 4 + rr;
              int ni = n0 + wn + fn * 16 + lr;
              float v = acc[fm][fn][rr] + cch * WF[srcO + (size_t)mi * LP + ni];
              WF[dstO + (size_t)mi * LP + ni] = v;
              WB[dstO + (size_t)mi * LP + ni] = f2b(v);
            }
      }
    }
    gbar(cnt, gen, ++barid);
  }

  // ================= P6: L6 chain W32..63 (448) || kd j=0..31 (448) =================
  for (int task = bid; task < 896; task += nb) {
    if (task < 448) {
      f32x4 acc[2][2];
      const int wv = tid >> 6, lane = tid & 63;
      const int wm = (wv >> 1) * 32, wn = (wv & 1) * 32;
      const int lr = lane & 15, lg = lane >> 4;
      const int t = task / 14, n0 = (task % 14) * 64;
      gemm64(WB + (size_t)t * WSZ, EN[5], LP, 14, 0, 0, n0, tid, As, Bs, acc);
      const size_t srcO = (size_t)t * WSZ, dstO = (size_t)(t + 32) * WSZ;
#pragma unroll
      for (int fm = 0; fm < 2; ++fm)
#pragma unroll
        for (int fn = 0; fn < 2; ++fn)
#pragma unroll
          for (int rr = 0; rr < 4; ++rr) {
            int mi = wm + fm * 16 + lg * 4 + rr;
            int ni = n0 + wn + fn * 16 + lr;
            float v = acc[fm][fn][rr] + cp[5] * WF[srcO + (size_t)mi * LP + ni];
            WF[dstO + (size_t)mi * LP + ni] = v;
            WB[dstO + (size_t)mi * LP + ni] = f2b(v);
          }
    } else {
      int j = (task - 448) / 14, l0 = ((task - 448) % 14) * 64;
      kd_body(WF, KDT, j, l0, tid, (float(*)[65])smemRaw);
    }
  }
  gbar(cnt, gen, ++barid);

  // ================= P7: kd j=32..63 =================
  for (int task = bid; task < 448; task += nb) {
    int j = 32 + task / 14, l0 = (task % 14) * 64;
    kd_body(WF, KDT, j, l0, tid, (float(*)[65])smemRaw);
  }
  gbar(cnt, gen, ++barid);

  // ================= P8: conv part[z] = U . KDT^T (chunked K) =================
  for (int task = bid; task < 56 * NZ; task += nb) {
    f32x4 acc[2][2];
    const int wv = tid >> 6, lane = tid & 63;
    const int wm = (wv >> 1) * 32, wn = (wv & 1) * 32;
    const int lr = lane & 15, lg = lane >> 4;
    const int z = task / 56, rem = task % 56;
    const int m0 = (rem / 14) * 64, n0 = (rem % 14) * 64;
    gemm64(U, KDT, KCV, 16, z * 1024, m0, n0, tid, As, Bs, acc);
    float* pp = part + (size_t)z * (256 * LP);
#pragma unroll
    for (int fm = 0; fm < 2; ++fm)
#pragma unroll
      for (int fn = 0; fn < 2; ++fn)
#pragma unroll
        for (int rr = 0; rr < 4; ++rr) {
          int m = m0 + wm + fm * 16 + lg * 4 + rr;
          int n = n0 + wn + fn * 16 + lr;
          pp[(size_t)m * LP + n] = acc[fm][fn][rr];
        }
  }
  gbar(cnt, gen, ++barid);

  // ================= P9: assemble theta row in LDS + decode =================
  for (int task = bid; task < 256; task += nb) {
    float* th = (float*)smemRaw;
    const int bt = task, b = bt >> 6, t = bt & 63;
    __syncthreads();
    for (int l = tid; l < LP; l += 256) {
      float v = 0.f;
      if (l < L) {
        if (t == 0) v = th0[l];
        else {
          int rr = b * 63 + (t - 1);
          v = part[(size_t)rr * LP + l]
            + part[(size_t)(256 * LP) + rr * LP + l]
            + part[(size_t)(2 * 256 * LP) + rr * LP + l];
          int tau = t - 1;
          v += WF[(size_t)tau * WSZ + DS * LP + l];
          int tw = (tau + 62) % 63;
          v += WF[(size_t)tw * WSZ + (49 + b) * LP + l];
        }
      }
      th[l] = v;
    }
    __syncthreads();
    if (tid < OUTD) {
      int o = tid;
      float tv = ts[bt];
      float acc = th[784 + o];
#pragma unroll
      for (int i = 0; i < 8; ++i) {
        float h = fmaxf(th[i] * tv + th[8 + i], 0.f);
        acc += th[16 + o * 8 + i] * h;
      }
      float rs;
      if (o < DS) rs = tanhf(acc);
      else        rs = fmaxf(acc, 0.f) + log1pf(expf(-fabsf(acc)));
      out[bt * OUTD + o] = rs;
    }
    __syncthreads();
  }
}

extern "C" void kernel_launch(void* const* d_in, const int* in_sizes, int n_in,
                              void* d_out, int out_size, void* d_ws, size_t ws_size,
                              hipStream_t stream) {
  const float* xs  = (const float*)d_in[0];
  const float* ts  = (const float*)d_in[1];
  const float* th0 = (const float*)d_in[2];
  const float* A   = (const float*)d_in[3];
  const float* B   = (const float*)d_in[4];
  float* ws  = (float*)d_ws;
  float* out = (float*)d_out;

  k_init<<<1, 64, 0, stream>>>((int*)(ws + OFF_BAR));
  mega<<<NBLK, 256, 0, stream>>>(xs, ts, th0, A, B, ws, out);
}